// Round 5
// baseline (109.933 us; speedup 1.0000x reference)
//
#include <hip/hip_runtime.h>
#include <math.h>

// TripletLoss semi-hard mining, N=512, D=512, C=64.
// v5: ONE fused kernel (+128B memset for counters).
//   Block (bi,bj) of a 16x16 grid:
//     phase 1: load its 64 fp32 rows, split to bf16 hi/lo in LDS (in-register),
//              per-stripe norms, 32x32 Gram tile via 3 MFMAs/k-step
//              (hi*hi + hi*lo + lo*hi), D tile -> ws.
//     phase 2: release-fence + stripe counter; the 16th block of each row
//              stripe acquire-fences and mines its 32 rows (v4-verified
//              semantics); last mining block finalizes the scalar output.
// For each ordered positive pair (j,a):
//   neg = min{ d[j][k] : lbl[k]!=lbl[j], d[j][k] > d[j][a] }
//         else max{ d[j][k] : lbl[k]!=lbl[j] } (0 if none)
//   loss += max(0, MARGIN + d[j][a] - neg);  out = loss / (numpos + 1e-8)

#define NN 512
#define MARGIN_F 0.2f
#define LK 520                    // LDS row stride in shorts (pad 8)

typedef __attribute__((ext_vector_type(8))) short bf16x8;
typedef __attribute__((ext_vector_type(4))) float f32x4;

__device__ __forceinline__ unsigned short f2bf(float x){
    unsigned u = __float_as_uint(x);
    return (unsigned short)((u + 0x7FFFu + ((u >> 16) & 1u)) >> 16);   // RNE
}
__device__ __forceinline__ float bf2f(unsigned short h){
    return __uint_as_float(((unsigned)h) << 16);
}

// ctrl (ints): [0..15] stripe counters, [16] done, [17] loss f32, [18] cnt u32
__global__ __launch_bounds__(256, 1) void k_fused(
    const int* __restrict__ labels,
    const float* __restrict__ emb,
    float* __restrict__ Dm,
    int* __restrict__ ctrl,
    float* __restrict__ out)
{
    __shared__ __align__(16) char sm[133376];
    short* sh  = (short*)sm;                      // [4][32][LK] hi/lo of I/J
    float* snI = (float*)(sm + 133120);           // [32]
    float* snJ = snI + 32;                        // [32]
    // phase-2 overlay (only used after all phase-1 LDS reads are done)
    int* slbl            = (int*)sm;                              // [512]
    float* drow          = (float*)(sm + 2048);                   // [4][512]
    unsigned short* plist = (unsigned short*)(sm + 2048 + 8192);  // [4][128]
    int* pcnt            = (int*)(sm + 2048 + 8192 + 1024);       // [4]
    int* sflag           = pcnt + 4;

    const int tid  = threadIdx.x;
    const int wave = tid >> 6, lane = tid & 63;
    const int bi = blockIdx.x >> 4, bj = blockIdx.x & 15;

    // ---- phase 1a: fp32 -> bf16 hi/lo staging + row norms ----
    {
        const int row = tid >> 3;                 // 0..31 (local row)
        const int s8  = tid & 7;
        const float4* Ep = (const float4*)emb;    // 128 float4 per row
        float ssI = 0.f, ssJ = 0.f;
        #pragma unroll
        for (int i = 0; i < 16; ++i) {
            const int c4 = s8 + (i << 3);         // f4 index 0..127
            const float4 vI = Ep[(size_t)(bi * 32 + row) * 128 + c4];
            const float4 vJ = Ep[(size_t)(bj * 32 + row) * 128 + c4];
            ssI = fmaf(vI.x, vI.x, ssI); ssI = fmaf(vI.y, vI.y, ssI);
            ssI = fmaf(vI.z, vI.z, ssI); ssI = fmaf(vI.w, vI.w, ssI);
            ssJ = fmaf(vJ.x, vJ.x, ssJ); ssJ = fmaf(vJ.y, vJ.y, ssJ);
            ssJ = fmaf(vJ.z, vJ.z, ssJ); ssJ = fmaf(vJ.w, vJ.w, ssJ);
            ushort4 h, l;
            h.x = f2bf(vI.x); l.x = f2bf(vI.x - bf2f(h.x));
            h.y = f2bf(vI.y); l.y = f2bf(vI.y - bf2f(h.y));
            h.z = f2bf(vI.z); l.z = f2bf(vI.z - bf2f(h.z));
            h.w = f2bf(vI.w); l.w = f2bf(vI.w - bf2f(h.w));
            *(ushort4*)(&sh[(0 * 32 + row) * LK + (c4 << 2)]) = h;
            *(ushort4*)(&sh[(1 * 32 + row) * LK + (c4 << 2)]) = l;
            h.x = f2bf(vJ.x); l.x = f2bf(vJ.x - bf2f(h.x));
            h.y = f2bf(vJ.y); l.y = f2bf(vJ.y - bf2f(h.y));
            h.z = f2bf(vJ.z); l.z = f2bf(vJ.z - bf2f(h.z));
            h.w = f2bf(vJ.w); l.w = f2bf(vJ.w - bf2f(h.w));
            *(ushort4*)(&sh[(2 * 32 + row) * LK + (c4 << 2)]) = h;
            *(ushort4*)(&sh[(3 * 32 + row) * LK + (c4 << 2)]) = l;
        }
        ssI += __shfl_xor(ssI, 1, 64); ssJ += __shfl_xor(ssJ, 1, 64);
        ssI += __shfl_xor(ssI, 2, 64); ssJ += __shfl_xor(ssJ, 2, 64);
        ssI += __shfl_xor(ssI, 4, 64); ssJ += __shfl_xor(ssJ, 4, 64);
        if (s8 == 0) { snI[row] = ssI; snJ[row] = ssJ; }
    }
    __syncthreads();

    // ---- phase 1b: 32x32 Gram tile, wave = one 16x16 quadrant ----
    const int rowb = (wave >> 1) << 4, colb = (wave & 1) << 4;
    const int fr = lane & 15;
    const int k0 = (lane >> 4) << 3;
    f32x4 acc = {0.f, 0.f, 0.f, 0.f};
    #pragma unroll
    for (int t8 = 0; t8 < 16; ++t8) {
        const int k = k0 + (t8 << 5);
        bf16x8 ahi = *(const bf16x8*)(&sh[(0 * 32 + rowb + fr) * LK + k]);
        bf16x8 alo = *(const bf16x8*)(&sh[(1 * 32 + rowb + fr) * LK + k]);
        bf16x8 bhi = *(const bf16x8*)(&sh[(2 * 32 + colb + fr) * LK + k]);
        bf16x8 blo = *(const bf16x8*)(&sh[(3 * 32 + colb + fr) * LK + k]);
        acc = __builtin_amdgcn_mfma_f32_16x16x32_bf16(ahi, bhi, acc, 0, 0, 0);
        acc = __builtin_amdgcn_mfma_f32_16x16x32_bf16(ahi, blo, acc, 0, 0, 0);
        acc = __builtin_amdgcn_mfma_f32_16x16x32_bf16(alo, bhi, acc, 0, 0, 0);
    }
    // epilogue: C/D layout col=lane&15, row=(lane>>4)*4+reg (m89-verified)
    {
        const int colg = bj * 32 + colb + fr;
        const float sc = snJ[colb + fr];
        const int rl0 = rowb + ((lane >> 4) << 2);
        #pragma unroll
        for (int reg = 0; reg < 4; ++reg) {
            const int rl = rl0 + reg;
            const float d2 = snI[rl] + sc - 2.f * acc[reg];
            Dm[(size_t)(bi * 32 + rl) * NN + colg] = sqrtf(fmaxf(d2, 0.f));
        }
    }

    // ---- release + stripe completion ----
    __syncthreads();                       // all tile stores issued (vmcnt drained)
    if (tid == 0) {
        __threadfence();                   // writeback to coherent point
        const int o = atomicAdd(&ctrl[bi], 1);
        *sflag = (o == 15);
    }
    __syncthreads();
    if (!*sflag) return;                   // 240 blocks done
    __threadfence();                       // acquire: invalidate stale caches

    // ---- phase 2: mine 32 rows of stripe bi (v4-verified semantics) ----
    slbl[tid] = labels[tid];
    slbl[tid + 256] = labels[tid + 256];
    __syncthreads();

    int lb[8];
    #pragma unroll
    for (int m = 0; m < 8; ++m) lb[m] = slbl[lane * 8 + m];

    float wloss = 0.f;
    unsigned wcnt = 0;
    for (int rr = 0; rr < 8; ++rr) {
        const int j = bi * 32 + (wave << 3) + rr;
        const float4* rp = (const float4*)(Dm + (size_t)j * NN);
        const float4 va = rp[lane * 2], vb = rp[lane * 2 + 1];
        *(float4*)(&drow[wave * NN + lane * 8])     = va;
        *(float4*)(&drow[wave * NN + lane * 8 + 4]) = vb;
        const float d[8] = {va.x, va.y, va.z, va.w, vb.x, vb.y, vb.z, vb.w};
        const int lj = slbl[j];
        if (lane == 0) pcnt[wave] = 0;     // per-wave DS ops are in-order
        #pragma unroll
        for (int m = 0; m < 8; ++m) {
            const int k = lane * 8 + m;
            if (k != j && lb[m] == lj) {
                const int ix = atomicAdd(&pcnt[wave], 1);
                plist[wave * 128 + ix] = (unsigned short)k;
            }
        }
        float vmaxl = 0.f;                 // max over negatives (fallback)
        #pragma unroll
        for (int m = 0; m < 8; ++m) if (lb[m] != lj) vmaxl = fmaxf(vmaxl, d[m]);
        #pragma unroll
        for (int o = 32; o > 0; o >>= 1) vmaxl = fmaxf(vmaxl, __shfl_xor(vmaxl, o, 64));
        const int np = pcnt[wave];
        wcnt += (unsigned)np;
        for (int p = 0; p < np; ++p) {
            const int a = plist[wave * 128 + p];
            const float dpa = drow[wave * NN + a];
            float vm = 1e30f;              // min negative strictly beyond dpa
            #pragma unroll
            for (int m = 0; m < 8; ++m) {
                const bool c = (lb[m] != lj) && (d[m] > dpa);
                vm = c ? fminf(vm, d[m]) : vm;
            }
            #pragma unroll
            for (int o = 32; o > 0; o >>= 1) vm = fminf(vm, __shfl_xor(vm, o, 64));
            const float neg = (vm < 1e29f) ? vm : vmaxl;
            const float term = MARGIN_F + dpa - neg;
            if (lane == 0 && term > 0.f) wloss += term;
        }
    }
    if (lane == 0) {
        if (wloss != 0.f) atomicAdd((float*)&ctrl[17], wloss);
        if (wcnt) atomicAdd((unsigned int*)&ctrl[18], wcnt);
    }
    __syncthreads();
    if (tid == 0) {
        __threadfence();
        const int o = atomicAdd(&ctrl[16], 1);
        if (o == 15) {
            __threadfence();
            const float L = atomicAdd((float*)&ctrl[17], 0.f);
            const unsigned C = atomicAdd((unsigned int*)&ctrl[18], 0u);
            out[0] = L / ((float)C + 1e-8f);
        }
    }
}

extern "C" void kernel_launch(void* const* d_in, const int* in_sizes, int n_in,
                              void* d_out, int out_size, void* d_ws, size_t ws_size,
                              hipStream_t stream) {
    (void)in_sizes; (void)n_in; (void)out_size; (void)ws_size;
    const int* labels = (const int*)d_in[0];
    const float* emb  = (const float*)d_in[1];
    char* ws = (char*)d_ws;
    float* Dm  = (float*)ws;                      // 1 MB
    int*   ctrl = (int*)(ws + (1u << 20));        // 19 ints

    hipMemsetAsync(ctrl, 0, 128, stream);
    k_fused<<<256, 256, 0, stream>>>(labels, emb, Dm, ctrl, (float*)d_out);
}

// Round 6
// 102.458 us; speedup vs baseline: 1.0729x; 1.0729x over previous
//
#include <hip/hip_runtime.h>
#include <math.h>

// TripletLoss semi-hard mining, N=512, D=512, C=64.
// v6: 32 fully independent blocks (one 16-row stripe each), everything
// block-local: A(own rows, bf16 hi/lo, full K) in LDS, B streamed as
// 128col x 128K tiles, Gram via 3 MFMAs/k-step (hi*hi + hi*lo + lo*hi),
// D stripe lives ONLY in LDS, mining = v4-verified semantics.
// Cross-block: two device atomics + done-counter; ordering enforced by
// consuming the atomics' return values (vmcnt drain) — NO threadfence
// (v5 post-mortem: agent fences = whole-L2 wb/inv, 256 of them = 50 us).
// For each ordered positive pair (j,a):
//   neg = min{ d[j][k] : lbl[k]!=lbl[j], d[j][k] > d[j][a] }
//         else max{ d[j][k] : lbl[k]!=lbl[j] } (0 if none)
//   loss += max(0, MARGIN + d[j][a] - neg);  out = loss / (numpos + 1e-8)

#define NN 512
#define MARGIN_F 0.2f
#define ASTR 520                 // A stride (shorts) / drows stride (floats)
#define BSTR 136                 // B tile stride (shorts)

// LDS byte offsets
#define AHI_OFF   0              // 16*520*2 = 16640
#define ALO_OFF   16640
#define BHI_OFF   33280          // 128*136*2 = 34816
#define BLO_OFF   68096
#define DR_OFF    102912         // 16*520*4 = 33280
#define SNA_OFF   136192         // 16 f32
#define SNB_OFF   136256         // 128 f32
#define SLBL_OFF  136768         // 512 i32
#define PLIST_OFF 138816         // 8*128 u16
#define PCNT_OFF  140864         // 8 i32
#define BL_OFF    140896         // f32
#define BC_OFF    140900         // i32
#define SM_BYTES  140928

typedef __attribute__((ext_vector_type(8))) short bf16x8;
typedef __attribute__((ext_vector_type(4))) float f32x4;

// split v into bf16-hi (RNE, packed pair-wise) + fp32 residual
__device__ __forceinline__ uint2 split_hi(const float4 v, float4* r) {
    const unsigned u0 = __float_as_uint(v.x), u1 = __float_as_uint(v.y),
                   u2 = __float_as_uint(v.z), u3 = __float_as_uint(v.w);
    const unsigned t0 = u0 + 0x7FFFu + ((u0 >> 16) & 1u);
    const unsigned t1 = u1 + 0x7FFFu + ((u1 >> 16) & 1u);
    const unsigned t2 = u2 + 0x7FFFu + ((u2 >> 16) & 1u);
    const unsigned t3 = u3 + 0x7FFFu + ((u3 >> 16) & 1u);
    uint2 h;
    h.x = (t0 >> 16) | (t1 & 0xFFFF0000u);
    h.y = (t2 >> 16) | (t3 & 0xFFFF0000u);
    r->x = v.x - __uint_as_float(t0 & 0xFFFF0000u);
    r->y = v.y - __uint_as_float(t1 & 0xFFFF0000u);
    r->z = v.z - __uint_as_float(t2 & 0xFFFF0000u);
    r->w = v.w - __uint_as_float(t3 & 0xFFFF0000u);
    return h;
}
// truncation-pack residual to bf16 (error 2^-15 relative to original — negligible)
__device__ __forceinline__ uint2 pack_lo(const float4 r) {
    uint2 l;
    l.x = (__float_as_uint(r.x) >> 16) | (__float_as_uint(r.y) & 0xFFFF0000u);
    l.y = (__float_as_uint(r.z) >> 16) | (__float_as_uint(r.w) & 0xFFFF0000u);
    return l;
}

__global__ __launch_bounds__(512) void k_fused(
    const int* __restrict__ labels,
    const float* __restrict__ emb,
    int* __restrict__ ctrl,        // [0]=loss f32, [1]=cnt u32, [2]=done u32
    float* __restrict__ out)
{
    __shared__ __align__(16) char sm[SM_BYTES];
    short* Ahi  = (short*)(sm + AHI_OFF);
    short* Alo  = (short*)(sm + ALO_OFF);
    short* Bhi  = (short*)(sm + BHI_OFF);
    short* Blo  = (short*)(sm + BLO_OFF);
    float* drows = (float*)(sm + DR_OFF);
    float* snA  = (float*)(sm + SNA_OFF);
    float* snB  = (float*)(sm + SNB_OFF);
    int*   slbl = (int*)(sm + SLBL_OFF);
    unsigned short* plist = (unsigned short*)(sm + PLIST_OFF);
    int*   pcnt = (int*)(sm + PCNT_OFF);
    float* bloss = (float*)(sm + BL_OFF);
    int*   bcnt  = (int*)(sm + BC_OFF);

    const int tid  = threadIdx.x;
    const int wave = tid >> 6, lane = tid & 63;
    const int bi = blockIdx.x;

    slbl[tid] = labels[tid];
    if (tid == 0) { *bloss = 0.f; *bcnt = 0; }

    // ---- phase A: own 16 rows -> Ahi/Alo, row norms (fp32-exact) ----
    {
        const int row = tid >> 5;            // 0..15
        const int c0  = tid & 31;
        float ss = 0.f;
        #pragma unroll
        for (int i = 0; i < 4; ++i) {
            const int f4 = c0 + (i << 5);    // 0..127
            const float4 v = ((const float4*)emb)[(size_t)(bi * 16 + row) * 128 + f4];
            ss = fmaf(v.x, v.x, ss); ss = fmaf(v.y, v.y, ss);
            ss = fmaf(v.z, v.z, ss); ss = fmaf(v.w, v.w, ss);
            float4 r; const uint2 h = split_hi(v, &r); const uint2 l = pack_lo(r);
            *(uint2*)(&Ahi[row * ASTR + (f4 << 2)]) = h;
            *(uint2*)(&Alo[row * ASTR + (f4 << 2)]) = l;
        }
        ss += __shfl_xor(ss, 1, 64);  ss += __shfl_xor(ss, 2, 64);
        ss += __shfl_xor(ss, 4, 64);  ss += __shfl_xor(ss, 8, 64);
        ss += __shfl_xor(ss, 16, 64);
        if ((tid & 31) == 0) snA[row] = ss;
    }

    // ---- phase B: 4 col-chunks x 4 K-chunks ----
    const int fr = lane & 15;
    const int kq = (lane >> 4) << 3;         // 0,8,16,24
    const int brow = tid >> 2;               // 0..127 (B tile row = Gram col)
    const int bf0  = tid & 3;

    for (int cc = 0; cc < 4; ++cc) {
        f32x4 acc = {0.f, 0.f, 0.f, 0.f};
        float bss = 0.f;                     // col-norm partial (fp32-exact)
        for (int kc = 0; kc < 4; ++kc) {
            __syncthreads();                 // B buffer free to overwrite
            #pragma unroll
            for (int u = 0; u < 8; ++u) {
                const int f4 = bf0 + (u << 2);   // 0..31
                const float4 v = ((const float4*)emb)[
                    (size_t)(cc * 128 + brow) * 128 + kc * 32 + f4];
                bss = fmaf(v.x, v.x, bss); bss = fmaf(v.y, v.y, bss);
                bss = fmaf(v.z, v.z, bss); bss = fmaf(v.w, v.w, bss);
                float4 r; const uint2 h = split_hi(v, &r); const uint2 l = pack_lo(r);
                *(uint2*)(&Bhi[brow * BSTR + (f4 << 2)]) = h;
                *(uint2*)(&Blo[brow * BSTR + (f4 << 2)]) = l;
            }
            __syncthreads();
            #pragma unroll
            for (int s = 0; s < 4; ++s) {
                const int kl = kq + (s << 5);        // 0..120
                const int kg = kc * 128 + kl;
                const bf16x8 ah = *(const bf16x8*)(&Ahi[fr * ASTR + kg]);
                const bf16x8 al = *(const bf16x8*)(&Alo[fr * ASTR + kg]);
                const bf16x8 bh = *(const bf16x8*)(&Bhi[(wave * 16 + fr) * BSTR + kl]);
                const bf16x8 bl = *(const bf16x8*)(&Blo[(wave * 16 + fr) * BSTR + kl]);
                acc = __builtin_amdgcn_mfma_f32_16x16x32_bf16(ah, bh, acc, 0, 0, 0);
                acc = __builtin_amdgcn_mfma_f32_16x16x32_bf16(ah, bl, acc, 0, 0, 0);
                acc = __builtin_amdgcn_mfma_f32_16x16x32_bf16(al, bh, acc, 0, 0, 0);
            }
        }
        // col norms for this chunk (quad reduce over bf0)
        bss += __shfl_xor(bss, 1, 64);
        bss += __shfl_xor(bss, 2, 64);
        if (bf0 == 0) snB[brow] = bss;
        __syncthreads();                     // snB ready; all B reads done
        // epilogue: C/D layout col=lane&15, row=(lane>>4)*4+reg (m89-verified)
        {
            const int cl = wave * 16 + fr;   // 0..127 within chunk
            const float sc = snB[cl];
            const int colg = cc * 128 + cl;
            const int r0 = (lane >> 4) << 2;
            #pragma unroll
            for (int reg = 0; reg < 4; ++reg) {
                const float d2 = snA[r0 + reg] + sc - 2.f * acc[reg];
                drows[(r0 + reg) * ASTR + colg] = sqrtf(fmaxf(d2, 0.f));
            }
        }
    }
    __syncthreads();                         // full D stripe in LDS

    // ---- mining: 8 waves x 2 rows (v4-verified semantics) ----
    int lb[8];
    #pragma unroll
    for (int m = 0; m < 8; ++m) lb[m] = slbl[lane * 8 + m];

    float wloss = 0.f; unsigned wcnt = 0;
    #pragma unroll
    for (int rr = 0; rr < 2; ++rr) {
        const int jl = wave * 2 + rr;
        const int jg = bi * 16 + jl;
        const float4 va = *(const float4*)(&drows[jl * ASTR + lane * 8]);
        const float4 vb = *(const float4*)(&drows[jl * ASTR + lane * 8 + 4]);
        const float d[8] = {va.x, va.y, va.z, va.w, vb.x, vb.y, vb.z, vb.w};
        const int lj = slbl[jg];
        if (lane == 0) pcnt[wave] = 0;       // per-wave DS ops are in-order
        #pragma unroll
        for (int m = 0; m < 8; ++m) {
            const int k = lane * 8 + m;
            if (k != jg && lb[m] == lj) {
                const int ix = atomicAdd(&pcnt[wave], 1);
                plist[wave * 128 + ix] = (unsigned short)k;
            }
        }
        float vmaxl = 0.f;                   // max over negatives (fallback)
        #pragma unroll
        for (int m = 0; m < 8; ++m) if (lb[m] != lj) vmaxl = fmaxf(vmaxl, d[m]);
        #pragma unroll
        for (int o = 32; o > 0; o >>= 1) vmaxl = fmaxf(vmaxl, __shfl_xor(vmaxl, o, 64));
        const int np = pcnt[wave];
        wcnt += (unsigned)np;
        for (int p = 0; p < np; ++p) {
            const int a = plist[wave * 128 + p];
            const float dpa = drows[jl * ASTR + a];
            float vm = 1e30f;                // min negative strictly beyond dpa
            #pragma unroll
            for (int m = 0; m < 8; ++m) {
                const bool c = (lb[m] != lj) && (d[m] > dpa);
                vm = c ? fminf(vm, d[m]) : vm;
            }
            #pragma unroll
            for (int o = 32; o > 0; o >>= 1) vm = fminf(vm, __shfl_xor(vm, o, 64));
            const float neg = (vm < 1e29f) ? vm : vmaxl;
            const float term = MARGIN_F + dpa - neg;
            if (lane == 0 && term > 0.f) wloss += term;
        }
    }
    if (lane == 0) {
        if (wloss != 0.f) atomicAdd(bloss, wloss);
        if (wcnt) atomicAdd(bcnt, (int)wcnt);
    }
    __syncthreads();

    // ---- cross-block scalar reduce: atomics only, no fences ----
    if (tid == 0) {
        const float    old  = atomicAdd((float*)&ctrl[0], *bloss);
        const unsigned oldc = atomicAdd((unsigned*)&ctrl[1], (unsigned)*bcnt);
        // consume returns: forces vmcnt drain (adds globally visible) before
        // the done-increment below issues. Condition is never true for real data.
        if ((__float_as_uint(old) ^ oldc) == 0xDEADBEEFu) out[0] = -1.f;
        const unsigned od = atomicAdd((unsigned*)&ctrl[2], 1u);
        if (od == 31u) {
            const float    L = atomicAdd((float*)&ctrl[0], 0.f);
            const unsigned C = atomicAdd((unsigned*)&ctrl[1], 0u);
            out[0] = L / ((float)C + 1e-8f);
        }
    }
}

extern "C" void kernel_launch(void* const* d_in, const int* in_sizes, int n_in,
                              void* d_out, int out_size, void* d_ws, size_t ws_size,
                              hipStream_t stream) {
    (void)in_sizes; (void)n_in; (void)out_size; (void)ws_size;
    const int* labels = (const int*)d_in[0];
    const float* emb  = (const float*)d_in[1];
    int* ctrl = (int*)d_ws;

    hipMemsetAsync(ctrl, 0, 128, stream);
    k_fused<<<32, 512, 0, stream>>>(labels, emb, ctrl, (float*)d_out);
}

// Round 7
// 79.068 us; speedup vs baseline: 1.3903x; 1.2958x over previous
//
#include <hip/hip_runtime.h>
#include <math.h>

// TripletLoss semi-hard mining, N=512, D=512, C=64.
// v7: two dispatches (v4's proven pipeline, trimmed).
//   k_dist: 16x16 grid of 32x32 tiles; each block loads its 64 fp32 rows,
//           converts to bf16 hi/lo in LDS (in-register), per-side norms,
//           Gram tile via 3 MFMAs/k-step (hi*hi + hi*lo + lo*hi),
//           D tile -> ws.  Block (0,0) zeroes the accumulators.
//   k_mine: per-row mining (v4-verified) + done-counter finalize.
// For each ordered positive pair (j,a):
//   neg = min{ d[j][k] : lbl[k]!=lbl[j], d[j][k] > d[j][a] }
//         else max{ d[j][k] : lbl[k]!=lbl[j] } (0 if none)
//   loss += max(0, MARGIN + d[j][a] - neg);  out = loss / (numpos + 1e-8)

#define NN 512
#define MARGIN_F 0.2f
#define LK 520                    // LDS row stride in shorts (pad 8)

typedef __attribute__((ext_vector_type(8))) short bf16x8;
typedef __attribute__((ext_vector_type(4))) float f32x4;

__device__ __forceinline__ unsigned short f2bf(float x){
    unsigned u = __float_as_uint(x);
    return (unsigned short)((u + 0x7FFFu + ((u >> 16) & 1u)) >> 16);   // RNE
}
__device__ __forceinline__ float bf2f(unsigned short h){
    return __uint_as_float(((unsigned)h) << 16);
}

// ---------------- k_dist: distance tiles (prep fused) ----------------
__global__ __launch_bounds__(256) void k_dist(
    const float* __restrict__ emb,
    float* __restrict__ Dm,
    int* __restrict__ ctrl)        // [0]=loss f32, [1]=cnt u32, [2]=done u32
{
    __shared__ __align__(16) char sm[133376];
    short* sh  = (short*)sm;                      // [4][32][LK] hi/lo of I/J
    float* snI = (float*)(sm + 133120);           // [32]
    float* snJ = snI + 32;                        // [32]

    const int tid  = threadIdx.x;
    const int wave = tid >> 6, lane = tid & 63;
    const int bi = blockIdx.y, bj = blockIdx.x;

    if (bi == 0 && bj == 0 && tid < 3) ctrl[tid] = 0;

    // ---- phase 1a: fp32 -> bf16 hi/lo staging + row norms (v5-verified) ----
    {
        const int row = tid >> 3;                 // 0..31 (local row)
        const int s8  = tid & 7;
        const float4* Ep = (const float4*)emb;    // 128 float4 per row
        float ssI = 0.f, ssJ = 0.f;
        #pragma unroll
        for (int i = 0; i < 16; ++i) {
            const int c4 = s8 + (i << 3);         // f4 index 0..127
            const float4 vI = Ep[(size_t)(bi * 32 + row) * 128 + c4];
            const float4 vJ = Ep[(size_t)(bj * 32 + row) * 128 + c4];
            ssI = fmaf(vI.x, vI.x, ssI); ssI = fmaf(vI.y, vI.y, ssI);
            ssI = fmaf(vI.z, vI.z, ssI); ssI = fmaf(vI.w, vI.w, ssI);
            ssJ = fmaf(vJ.x, vJ.x, ssJ); ssJ = fmaf(vJ.y, vJ.y, ssJ);
            ssJ = fmaf(vJ.z, vJ.z, ssJ); ssJ = fmaf(vJ.w, vJ.w, ssJ);
            ushort4 h, l;
            h.x = f2bf(vI.x); l.x = f2bf(vI.x - bf2f(h.x));
            h.y = f2bf(vI.y); l.y = f2bf(vI.y - bf2f(h.y));
            h.z = f2bf(vI.z); l.z = f2bf(vI.z - bf2f(h.z));
            h.w = f2bf(vI.w); l.w = f2bf(vI.w - bf2f(h.w));
            *(ushort4*)(&sh[(0 * 32 + row) * LK + (c4 << 2)]) = h;
            *(ushort4*)(&sh[(1 * 32 + row) * LK + (c4 << 2)]) = l;
            h.x = f2bf(vJ.x); l.x = f2bf(vJ.x - bf2f(h.x));
            h.y = f2bf(vJ.y); l.y = f2bf(vJ.y - bf2f(h.y));
            h.z = f2bf(vJ.z); l.z = f2bf(vJ.z - bf2f(h.z));
            h.w = f2bf(vJ.w); l.w = f2bf(vJ.w - bf2f(h.w));
            *(ushort4*)(&sh[(2 * 32 + row) * LK + (c4 << 2)]) = h;
            *(ushort4*)(&sh[(3 * 32 + row) * LK + (c4 << 2)]) = l;
        }
        ssI += __shfl_xor(ssI, 1, 64); ssJ += __shfl_xor(ssJ, 1, 64);
        ssI += __shfl_xor(ssI, 2, 64); ssJ += __shfl_xor(ssJ, 2, 64);
        ssI += __shfl_xor(ssI, 4, 64); ssJ += __shfl_xor(ssJ, 4, 64);
        if (s8 == 0) { snI[row] = ssI; snJ[row] = ssJ; }
    }
    __syncthreads();

    // ---- phase 1b: 32x32 Gram tile, wave = one 16x16 quadrant ----
    const int rowb = (wave >> 1) << 4, colb = (wave & 1) << 4;
    const int fr = lane & 15;
    const int k0 = (lane >> 4) << 3;
    f32x4 acc = {0.f, 0.f, 0.f, 0.f};
    #pragma unroll
    for (int t8 = 0; t8 < 16; ++t8) {
        const int k = k0 + (t8 << 5);
        bf16x8 ahi = *(const bf16x8*)(&sh[(0 * 32 + rowb + fr) * LK + k]);
        bf16x8 alo = *(const bf16x8*)(&sh[(1 * 32 + rowb + fr) * LK + k]);
        bf16x8 bhi = *(const bf16x8*)(&sh[(2 * 32 + colb + fr) * LK + k]);
        bf16x8 blo = *(const bf16x8*)(&sh[(3 * 32 + colb + fr) * LK + k]);
        acc = __builtin_amdgcn_mfma_f32_16x16x32_bf16(ahi, bhi, acc, 0, 0, 0);
        acc = __builtin_amdgcn_mfma_f32_16x16x32_bf16(ahi, blo, acc, 0, 0, 0);
        acc = __builtin_amdgcn_mfma_f32_16x16x32_bf16(alo, bhi, acc, 0, 0, 0);
    }
    // epilogue: C/D layout col=lane&15, row=(lane>>4)*4+reg (m89-verified)
    {
        const int colg = bj * 32 + colb + fr;
        const float sc = snJ[colb + fr];
        const int rl0 = rowb + ((lane >> 4) << 2);
        #pragma unroll
        for (int reg = 0; reg < 4; ++reg) {
            const int rl = rl0 + reg;
            const float d2 = snI[rl] + sc - 2.f * acc[reg];
            Dm[(size_t)(bi * 32 + rl) * NN + colg] = sqrtf(fmaxf(d2, 0.f));
        }
    }
}

// ---------------- k_mine: mining + finalize (v4-verified) ----------------
__global__ __launch_bounds__(256) void k_mine(
    const int* __restrict__ labels,
    const float* __restrict__ Dm,
    float* __restrict__ accums,          // [0]=loss [1]=cnt(u32) [2]=done(u32)
    float* __restrict__ out,
    int nblocks)
{
    __shared__ int slbl[NN];
    __shared__ float drow[4][NN];
    __shared__ unsigned short plist[4][128];
    __shared__ int pcnt[4];

    const int tid = threadIdx.x, wave = tid >> 6, lane = tid & 63;
    const int j = blockIdx.x * 4 + wave;

    slbl[tid] = labels[tid];
    slbl[tid + 256] = labels[tid + 256];
    if (tid < 4) pcnt[tid] = 0;
    __syncthreads();

    // distance row j: 8 values per lane in registers + LDS copy for dpa lookups
    const float4* rp = (const float4*)(Dm + (size_t)j * NN);
    const float4 va = rp[lane * 2], vb = rp[lane * 2 + 1];
    *(float4*)(&drow[wave][lane * 8]) = va;
    *(float4*)(&drow[wave][lane * 8 + 4]) = vb;
    float d[8] = {va.x, va.y, va.z, va.w, vb.x, vb.y, vb.z, vb.w};
    const int lj = slbl[j];
    int lb[8];
    #pragma unroll
    for (int m = 0; m < 8; ++m) lb[m] = slbl[lane * 8 + m];

    // positive list (wave-local LDS; in-order per-wave DS ops)
    #pragma unroll
    for (int m = 0; m < 8; ++m){
        const int k = lane * 8 + m;
        if (k != j && lb[m] == lj){
            const int ix = atomicAdd(&pcnt[wave], 1);
            plist[wave][ix] = (unsigned short)k;
        }
    }
    // max over negatives: dpa-independent, reduce once per row
    float vmaxl = 0.f;
    #pragma unroll
    for (int m = 0; m < 8; ++m) if (lb[m] != lj) vmaxl = fmaxf(vmaxl, d[m]);
    #pragma unroll
    for (int o = 32; o > 0; o >>= 1) vmaxl = fmaxf(vmaxl, __shfl_xor(vmaxl, o, 64));

    const int np = pcnt[wave];
    float wloss = 0.f;
    for (int p = 0; p < np; ++p){
        const int a = plist[wave][p];
        const float dpa = drow[wave][a];
        float vm = 1e30f;   // min negative strictly farther than dpa
        #pragma unroll
        for (int m = 0; m < 8; ++m){
            const bool cnd = (lb[m] != lj) && (d[m] > dpa);
            vm = cnd ? fminf(vm, d[m]) : vm;
        }
        #pragma unroll
        for (int o = 32; o > 0; o >>= 1) vm = fminf(vm, __shfl_xor(vm, o, 64));
        const float neg = (vm < 1e29f) ? vm : vmaxl;
        const float term = MARGIN_F + dpa - neg;
        if (lane == 0 && term > 0.f) wloss += term;
    }
    if (lane == 0){
        if (wloss != 0.f) atomicAdd(&accums[0], wloss);
        if (np) atomicAdd((unsigned int*)&accums[1], (unsigned int)np);
    }
    __syncthreads();
    if (tid == 0){
        __threadfence();
        const unsigned old = atomicAdd((unsigned int*)&accums[2], 1u);
        if (old == (unsigned)(nblocks - 1)){
            const float L = atomicAdd(&accums[0], 0.f);
            const unsigned C = atomicAdd((unsigned int*)&accums[1], 0u);
            out[0] = L / ((float)C + 1e-8f);
        }
    }
}

extern "C" void kernel_launch(void* const* d_in, const int* in_sizes, int n_in,
                              void* d_out, int out_size, void* d_ws, size_t ws_size,
                              hipStream_t stream) {
    (void)in_sizes; (void)n_in; (void)out_size; (void)ws_size;
    const int* labels = (const int*)d_in[0];
    const float* emb  = (const float*)d_in[1];
    char* ws = (char*)d_ws;
    float* Dm   = (float*)ws;                     // 1 MB
    int*   ctrl = (int*)(ws + (1u << 20));        // 3 ints

    k_dist<<<dim3(16, 16), 256, 0, stream>>>(emb, Dm, ctrl);
    k_mine<<<128, 256, 0, stream>>>(labels, Dm, (float*)ctrl, (float*)d_out, 128);
}

// Round 8
// 77.567 us; speedup vs baseline: 1.4173x; 1.0194x over previous
//
#include <hip/hip_runtime.h>
#include <math.h>

// TripletLoss semi-hard mining, N=512, D=512, C=64.
// v8: v7's two-dispatch pipeline; k_dist rebuilt for wave-TLP.
//   k_dist: 16x16 grid of 32x32 tiles, 512 threads (8 waves = 2/SIMD).
//           Staging: 64 fp32 rows -> bf16 hi/lo in LDS (in-register split),
//           per-side norms. MFMA: 4 quadrant-waves x 2 K-half-waves,
//           3 MFMAs/k-step (hi*hi + hi*lo + lo*hi); K-halves combined via
//           4KB LDS scratch. Block (0,0) zeroes accumulators.
//   k_mine: per-row mining (v4-verified, unchanged) + done-counter finalize.
// For each ordered positive pair (j,a):
//   neg = min{ d[j][k] : lbl[k]!=lbl[j], d[j][k] > d[j][a] }
//         else max{ d[j][k] : lbl[k]!=lbl[j] } (0 if none)
//   loss += max(0, MARGIN + d[j][a] - neg);  out = loss / (numpos + 1e-8)

#define NN 512
#define MARGIN_F 0.2f
#define LK 528                    // LDS row stride in shorts (264 words: 2-way-free writes)

typedef __attribute__((ext_vector_type(8))) short bf16x8;
typedef __attribute__((ext_vector_type(4))) float f32x4;

__device__ __forceinline__ unsigned short f2bf(float x){
    unsigned u = __float_as_uint(x);
    return (unsigned short)((u + 0x7FFFu + ((u >> 16) & 1u)) >> 16);   // RNE
}
__device__ __forceinline__ float bf2f(unsigned short h){
    return __uint_as_float(((unsigned)h) << 16);
}

// LDS byte offsets
#define SH_OFF   0                 // 4*32*528*2 = 135168
#define SNI_OFF  135168            // 32 f32
#define SNJ_OFF  135296            // 32 f32
#define SCR_OFF  135424            // 4*64*16 = 4096 (K-half partials)
#define SM_BYTES 139520

// ---------------- k_dist: distance tiles ----------------
__global__ __launch_bounds__(512) void k_dist(
    const float* __restrict__ emb,
    float* __restrict__ Dm,
    int* __restrict__ ctrl)        // [0]=loss f32, [1]=cnt u32, [2]=done u32
{
    __shared__ __align__(16) char sm[SM_BYTES];
    short* sh  = (short*)(sm + SH_OFF);           // [4][32][LK] Ihi/Ilo/Jhi/Jlo
    float* snI = (float*)(sm + SNI_OFF);
    float* snJ = (float*)(sm + SNJ_OFF);
    f32x4* scr = (f32x4*)(sm + SCR_OFF);          // [4][64]

    const int tid  = threadIdx.x;
    const int wave = tid >> 6, lane = tid & 63;
    const int bi = blockIdx.y, bj = blockIdx.x;

    if (bi == 0 && bj == 0 && tid < 3) ctrl[tid] = 0;

    // ---- staging: 64 rows (32 I + 32 J) fp32 -> bf16 hi/lo + norms ----
    {
        const int row = tid >> 3;                 // 0..63
        const int s8  = tid & 7;
        const int isJ = row >> 5;                 // 0:I 1:J
        const int rl  = row & 31;
        const int grow = (isJ ? bj : bi) * 32 + rl;
        const int bhi = (isJ << 1), blo = bhi + 1;
        const float4* Ep = (const float4*)emb;    // 128 float4 per row
        float ss = 0.f;
        #pragma unroll
        for (int i = 0; i < 16; ++i) {
            const int c4 = s8 + (i << 3);         // 0..127
            const float4 v = Ep[(size_t)grow * 128 + c4];
            ss = fmaf(v.x, v.x, ss); ss = fmaf(v.y, v.y, ss);
            ss = fmaf(v.z, v.z, ss); ss = fmaf(v.w, v.w, ss);
            ushort4 h, l;
            h.x = f2bf(v.x); l.x = f2bf(v.x - bf2f(h.x));
            h.y = f2bf(v.y); l.y = f2bf(v.y - bf2f(h.y));
            h.z = f2bf(v.z); l.z = f2bf(v.z - bf2f(h.z));
            h.w = f2bf(v.w); l.w = f2bf(v.w - bf2f(h.w));
            *(ushort4*)(&sh[(bhi * 32 + rl) * LK + (c4 << 2)]) = h;
            *(ushort4*)(&sh[(blo * 32 + rl) * LK + (c4 << 2)]) = l;
        }
        ss += __shfl_xor(ss, 1, 64);
        ss += __shfl_xor(ss, 2, 64);
        ss += __shfl_xor(ss, 4, 64);
        if (s8 == 0) { if (isJ) snJ[rl] = ss; else snI[rl] = ss; }
    }
    __syncthreads();

    // ---- MFMA: quad = quadrant, khalf = K half ----
    const int quad = wave & 3, khalf = wave >> 2;
    const int rowb = (quad >> 1) << 4, colb = (quad & 1) << 4;
    const int fr = lane & 15;
    const int k0 = (lane >> 4) << 3;
    f32x4 acc = {0.f, 0.f, 0.f, 0.f};
    #pragma unroll
    for (int t8 = 0; t8 < 8; ++t8) {
        const int k = k0 + (((khalf << 3) + t8) << 5);
        const bf16x8 ahi = *(const bf16x8*)(&sh[(0 * 32 + rowb + fr) * LK + k]);
        const bf16x8 alo = *(const bf16x8*)(&sh[(1 * 32 + rowb + fr) * LK + k]);
        const bf16x8 bhi = *(const bf16x8*)(&sh[(2 * 32 + colb + fr) * LK + k]);
        const bf16x8 blo = *(const bf16x8*)(&sh[(3 * 32 + colb + fr) * LK + k]);
        acc = __builtin_amdgcn_mfma_f32_16x16x32_bf16(ahi, bhi, acc, 0, 0, 0);
        acc = __builtin_amdgcn_mfma_f32_16x16x32_bf16(ahi, blo, acc, 0, 0, 0);
        acc = __builtin_amdgcn_mfma_f32_16x16x32_bf16(alo, bhi, acc, 0, 0, 0);
    }
    if (khalf == 1) scr[quad * 64 + lane] = acc;
    __syncthreads();
    if (khalf == 0) {
        const f32x4 other = scr[quad * 64 + lane];
        acc[0] += other[0]; acc[1] += other[1];
        acc[2] += other[2]; acc[3] += other[3];
        // epilogue: C/D layout col=lane&15, row=(lane>>4)*4+reg (m89-verified)
        const int colg = bj * 32 + colb + fr;
        const float sc = snJ[colb + fr];
        const int rl0 = rowb + ((lane >> 4) << 2);
        #pragma unroll
        for (int reg = 0; reg < 4; ++reg) {
            const int rl = rl0 + reg;
            const float d2 = snI[rl] + sc - 2.f * acc[reg];
            Dm[(size_t)(bi * 32 + rl) * NN + colg] = sqrtf(fmaxf(d2, 0.f));
        }
    }
}

// ---------------- k_mine: mining + finalize (v4-verified) ----------------
__global__ __launch_bounds__(256) void k_mine(
    const int* __restrict__ labels,
    const float* __restrict__ Dm,
    float* __restrict__ accums,          // [0]=loss [1]=cnt(u32) [2]=done(u32)
    float* __restrict__ out,
    int nblocks)
{
    __shared__ int slbl[NN];
    __shared__ float drow[4][NN];
    __shared__ unsigned short plist[4][128];
    __shared__ int pcnt[4];

    const int tid = threadIdx.x, wave = tid >> 6, lane = tid & 63;
    const int j = blockIdx.x * 4 + wave;

    slbl[tid] = labels[tid];
    slbl[tid + 256] = labels[tid + 256];
    if (tid < 4) pcnt[tid] = 0;
    __syncthreads();

    // distance row j: 8 values per lane in registers + LDS copy for dpa lookups
    const float4* rp = (const float4*)(Dm + (size_t)j * NN);
    const float4 va = rp[lane * 2], vb = rp[lane * 2 + 1];
    *(float4*)(&drow[wave][lane * 8]) = va;
    *(float4*)(&drow[wave][lane * 8 + 4]) = vb;
    float d[8] = {va.x, va.y, va.z, va.w, vb.x, vb.y, vb.z, vb.w};
    const int lj = slbl[j];
    int lb[8];
    #pragma unroll
    for (int m = 0; m < 8; ++m) lb[m] = slbl[lane * 8 + m];

    // positive list (wave-local LDS; in-order per-wave DS ops)
    #pragma unroll
    for (int m = 0; m < 8; ++m){
        const int k = lane * 8 + m;
        if (k != j && lb[m] == lj){
            const int ix = atomicAdd(&pcnt[wave], 1);
            plist[wave][ix] = (unsigned short)k;
        }
    }
    // max over negatives: dpa-independent, reduce once per row
    float vmaxl = 0.f;
    #pragma unroll
    for (int m = 0; m < 8; ++m) if (lb[m] != lj) vmaxl = fmaxf(vmaxl, d[m]);
    #pragma unroll
    for (int o = 32; o > 0; o >>= 1) vmaxl = fmaxf(vmaxl, __shfl_xor(vmaxl, o, 64));

    const int np = pcnt[wave];
    float wloss = 0.f;
    for (int p = 0; p < np; ++p){
        const int a = plist[wave][p];
        const float dpa = drow[wave][a];
        float vm = 1e30f;   // min negative strictly farther than dpa
        #pragma unroll
        for (int m = 0; m < 8; ++m){
            const bool cnd = (lb[m] != lj) && (d[m] > dpa);
            vm = cnd ? fminf(vm, d[m]) : vm;
        }
        #pragma unroll
        for (int o = 32; o > 0; o >>= 1) vm = fminf(vm, __shfl_xor(vm, o, 64));
        const float neg = (vm < 1e29f) ? vm : vmaxl;
        const float term = MARGIN_F + dpa - neg;
        if (lane == 0 && term > 0.f) wloss += term;
    }
    if (lane == 0){
        if (wloss != 0.f) atomicAdd(&accums[0], wloss);
        if (np) atomicAdd((unsigned int*)&accums[1], (unsigned int)np);
    }
    __syncthreads();
    if (tid == 0){
        __threadfence();
        const unsigned old = atomicAdd((unsigned int*)&accums[2], 1u);
        if (old == (unsigned)(nblocks - 1)){
            const float L = atomicAdd(&accums[0], 0.f);
            const unsigned C = atomicAdd((unsigned int*)&accums[1], 0u);
            out[0] = L / ((float)C + 1e-8f);
        }
    }
}

extern "C" void kernel_launch(void* const* d_in, const int* in_sizes, int n_in,
                              void* d_out, int out_size, void* d_ws, size_t ws_size,
                              hipStream_t stream) {
    (void)in_sizes; (void)n_in; (void)out_size; (void)ws_size;
    const int* labels = (const int*)d_in[0];
    const float* emb  = (const float*)d_in[1];
    char* ws = (char*)d_ws;
    float* Dm   = (float*)ws;                     // 1 MB
    int*   ctrl = (int*)(ws + (1u << 20));        // 3 ints

    k_dist<<<dim3(16, 16), 512, 0, stream>>>(emb, Dm, ctrl);
    k_mine<<<128, 256, 0, stream>>>(labels, Dm, (float*)ctrl, (float*)d_out, 128);
}

// Round 9
// 76.699 us; speedup vs baseline: 1.4333x; 1.0113x over previous
//
#include <hip/hip_runtime.h>
#include <math.h>

// TripletLoss semi-hard mining, N=512, D=512, C=64.
// v9: v8's pipeline + SYMMETRY: only 136 upper-triangle 32x32 tiles are
// computed; each block writes its tile AND the transposed mirror tile
// (per-wave 16x17 LDS transpose, coalesced stores). Halves k_dist's
// aggregate staging fetch (32 MB -> ~16 MB) at unchanged per-block cost.
//   k_dist: 512 thr (2 waves/SIMD); stage 64 fp32 rows -> bf16 hi/lo in
//           LDS, norms; Gram via 3 MFMAs/k-step (hi*hi+hi*lo+lo*hi);
//           K halved across wave groups, combined via LDS scratch.
//   k_mine: per-row mining (v4-verified, unchanged) + done-counter finalize.
// For each ordered positive pair (j,a):
//   neg = min{ d[j][k] : lbl[k]!=lbl[j], d[j][k] > d[j][a] }
//         else max{ d[j][k] : lbl[k]!=lbl[j] } (0 if none)
//   loss += max(0, MARGIN + d[j][a] - neg);  out = loss / (numpos + 1e-8)

#define NN 512
#define MARGIN_F 0.2f
#define LK 528                    // LDS row stride in shorts

typedef __attribute__((ext_vector_type(8))) short bf16x8;
typedef __attribute__((ext_vector_type(4))) float f32x4;

__device__ __forceinline__ unsigned short f2bf(float x){
    unsigned u = __float_as_uint(x);
    return (unsigned short)((u + 0x7FFFu + ((u >> 16) & 1u)) >> 16);   // RNE
}
__device__ __forceinline__ float bf2f(unsigned short h){
    return __uint_as_float(((unsigned)h) << 16);
}

// LDS byte offsets
#define SH_OFF   0                 // 4*32*528*2 = 135168
#define SNI_OFF  135168            // 32 f32
#define SNJ_OFF  135296            // 32 f32
#define SCR_OFF  135424            // 4*64*16 = 4096 (K-half partials)
#define TRP_OFF  139520            // 4 * 16*17*4 = 4352 (per-wave transpose)
#define SM_BYTES 143872

// ---------------- k_dist: symmetric distance tiles ----------------
__global__ __launch_bounds__(512) void k_dist(
    const float* __restrict__ emb,
    float* __restrict__ Dm,
    int* __restrict__ ctrl)        // [0]=loss f32, [1]=cnt u32, [2]=done u32
{
    __shared__ __align__(16) char sm[SM_BYTES];
    short* sh  = (short*)(sm + SH_OFF);           // [4][32][LK] Ihi/Ilo/Jhi/Jlo
    float* snI = (float*)(sm + SNI_OFF);
    float* snJ = (float*)(sm + SNJ_OFF);
    f32x4* scr = (f32x4*)(sm + SCR_OFF);          // [4][64]
    float* trp = (float*)(sm + TRP_OFF);          // [4][16*17]

    const int tid  = threadIdx.x;
    const int wave = tid >> 6, lane = tid & 63;

    // triangle map: blockIdx.x in [0,136) -> (bi,bj), bi<=bj
    int t = blockIdx.x, bi = 0;
    #pragma unroll
    for (int r = 0; r < 16; ++r) {
        const int rowlen = 16 - r;
        if (t < rowlen) { bi = r; break; }
        t -= rowlen;
    }
    const int bj = bi + t;

    if (blockIdx.x == 0 && tid < 3) ctrl[tid] = 0;

    // ---- staging: 64 rows (32 I + 32 J) fp32 -> bf16 hi/lo + norms ----
    {
        const int row = tid >> 3;                 // 0..63
        const int s8  = tid & 7;
        const int isJ = row >> 5;                 // 0:I 1:J
        const int rl  = row & 31;
        const int grow = (isJ ? bj : bi) * 32 + rl;
        const int bhi = (isJ << 1), blo = bhi + 1;
        const float4* Ep = (const float4*)emb;    // 128 float4 per row
        float ss = 0.f;
        #pragma unroll
        for (int i = 0; i < 16; ++i) {
            const int c4 = s8 + (i << 3);         // 0..127
            const float4 v = Ep[(size_t)grow * 128 + c4];
            ss = fmaf(v.x, v.x, ss); ss = fmaf(v.y, v.y, ss);
            ss = fmaf(v.z, v.z, ss); ss = fmaf(v.w, v.w, ss);
            ushort4 h, l;
            h.x = f2bf(v.x); l.x = f2bf(v.x - bf2f(h.x));
            h.y = f2bf(v.y); l.y = f2bf(v.y - bf2f(h.y));
            h.z = f2bf(v.z); l.z = f2bf(v.z - bf2f(h.z));
            h.w = f2bf(v.w); l.w = f2bf(v.w - bf2f(h.w));
            *(ushort4*)(&sh[(bhi * 32 + rl) * LK + (c4 << 2)]) = h;
            *(ushort4*)(&sh[(blo * 32 + rl) * LK + (c4 << 2)]) = l;
        }
        ss += __shfl_xor(ss, 1, 64);
        ss += __shfl_xor(ss, 2, 64);
        ss += __shfl_xor(ss, 4, 64);
        if (s8 == 0) { if (isJ) snJ[rl] = ss; else snI[rl] = ss; }
    }
    __syncthreads();

    // ---- MFMA: quad = quadrant, khalf = K half ----
    const int quad = wave & 3, khalf = wave >> 2;
    const int rowb = (quad >> 1) << 4, colb = (quad & 1) << 4;
    const int fr = lane & 15;
    const int q4 = lane >> 4;                     // 0..3
    const int k0 = q4 << 3;
    f32x4 acc = {0.f, 0.f, 0.f, 0.f};
    #pragma unroll
    for (int t8 = 0; t8 < 8; ++t8) {
        const int k = k0 + (((khalf << 3) + t8) << 5);
        const bf16x8 ahi = *(const bf16x8*)(&sh[(0 * 32 + rowb + fr) * LK + k]);
        const bf16x8 alo = *(const bf16x8*)(&sh[(1 * 32 + rowb + fr) * LK + k]);
        const bf16x8 bhi = *(const bf16x8*)(&sh[(2 * 32 + colb + fr) * LK + k]);
        const bf16x8 blo = *(const bf16x8*)(&sh[(3 * 32 + colb + fr) * LK + k]);
        acc = __builtin_amdgcn_mfma_f32_16x16x32_bf16(ahi, bhi, acc, 0, 0, 0);
        acc = __builtin_amdgcn_mfma_f32_16x16x32_bf16(ahi, blo, acc, 0, 0, 0);
        acc = __builtin_amdgcn_mfma_f32_16x16x32_bf16(alo, bhi, acc, 0, 0, 0);
    }
    if (khalf == 1) scr[quad * 64 + lane] = acc;
    __syncthreads();
    if (khalf == 0) {
        const f32x4 other = scr[quad * 64 + lane];
        acc[0] += other[0]; acc[1] += other[1];
        acc[2] += other[2]; acc[3] += other[3];
        // C/D layout col=lane&15, row=(lane>>4)*4+reg (m89-verified)
        const int colg = bj * 32 + colb + fr;
        const float sc = snJ[colb + fr];
        const int rl0 = rowb + (q4 << 2);
        float dv[4];
        #pragma unroll
        for (int reg = 0; reg < 4; ++reg) {
            const int rl = rl0 + reg;
            const float d2 = snI[rl] + sc - 2.f * acc[reg];
            dv[reg] = sqrtf(fmaxf(d2, 0.f));
            Dm[(size_t)(bi * 32 + rl) * NN + colg] = dv[reg];
        }
        // mirror tile via per-wave 16x17 transpose (intra-wave LDS only)
        float* T = trp + quad * (16 * 17);
        #pragma unroll
        for (int reg = 0; reg < 4; ++reg)
            T[fr * 17 + (q4 << 2) + reg] = dv[reg];   // T[col][row] = d(row,col)
        #pragma unroll
        for (int reg = 0; reg < 4; ++reg) {
            const float m = T[((q4 << 2) + reg) * 17 + fr];   // d(fr, 4q+reg)
            const int mrow = bj * 32 + colb + (q4 << 2) + reg;
            const int mcol = bi * 32 + rowb + fr;
            Dm[(size_t)mrow * NN + mcol] = m;
        }
    }
}

// ---------------- k_mine: mining + finalize (v4-verified) ----------------
__global__ __launch_bounds__(256) void k_mine(
    const int* __restrict__ labels,
    const float* __restrict__ Dm,
    float* __restrict__ accums,          // [0]=loss [1]=cnt(u32) [2]=done(u32)
    float* __restrict__ out,
    int nblocks)
{
    __shared__ int slbl[NN];
    __shared__ float drow[4][NN];
    __shared__ unsigned short plist[4][128];
    __shared__ int pcnt[4];

    const int tid = threadIdx.x, wave = tid >> 6, lane = tid & 63;
    const int j = blockIdx.x * 4 + wave;

    slbl[tid] = labels[tid];
    slbl[tid + 256] = labels[tid + 256];
    if (tid < 4) pcnt[tid] = 0;
    __syncthreads();

    // distance row j: 8 values per lane in registers + LDS copy for dpa lookups
    const float4* rp = (const float4*)(Dm + (size_t)j * NN);
    const float4 va = rp[lane * 2], vb = rp[lane * 2 + 1];
    *(float4*)(&drow[wave][lane * 8]) = va;
    *(float4*)(&drow[wave][lane * 8 + 4]) = vb;
    float d[8] = {va.x, va.y, va.z, va.w, vb.x, vb.y, vb.z, vb.w};
    const int lj = slbl[j];
    int lb[8];
    #pragma unroll
    for (int m = 0; m < 8; ++m) lb[m] = slbl[lane * 8 + m];

    // positive list (wave-local LDS; in-order per-wave DS ops)
    #pragma unroll
    for (int m = 0; m < 8; ++m){
        const int k = lane * 8 + m;
        if (k != j && lb[m] == lj){
            const int ix = atomicAdd(&pcnt[wave], 1);
            plist[wave][ix] = (unsigned short)k;
        }
    }
    // max over negatives: dpa-independent, reduce once per row
    float vmaxl = 0.f;
    #pragma unroll
    for (int m = 0; m < 8; ++m) if (lb[m] != lj) vmaxl = fmaxf(vmaxl, d[m]);
    #pragma unroll
    for (int o = 32; o > 0; o >>= 1) vmaxl = fmaxf(vmaxl, __shfl_xor(vmaxl, o, 64));

    const int np = pcnt[wave];
    float wloss = 0.f;
    for (int p = 0; p < np; ++p){
        const int a = plist[wave][p];
        const float dpa = drow[wave][a];
        float vm = 1e30f;   // min negative strictly farther than dpa
        #pragma unroll
        for (int m = 0; m < 8; ++m){
            const bool cnd = (lb[m] != lj) && (d[m] > dpa);
            vm = cnd ? fminf(vm, d[m]) : vm;
        }
        #pragma unroll
        for (int o = 32; o > 0; o >>= 1) vm = fminf(vm, __shfl_xor(vm, o, 64));
        const float neg = (vm < 1e29f) ? vm : vmaxl;
        const float term = MARGIN_F + dpa - neg;
        if (lane == 0 && term > 0.f) wloss += term;
    }
    if (lane == 0){
        if (wloss != 0.f) atomicAdd(&accums[0], wloss);
        if (np) atomicAdd((unsigned int*)&accums[1], (unsigned int)np);
    }
    __syncthreads();
    if (tid == 0){
        __threadfence();
        const unsigned old = atomicAdd((unsigned int*)&accums[2], 1u);
        if (old == (unsigned)(nblocks - 1)){
            const float L = atomicAdd(&accums[0], 0.f);
            const unsigned C = atomicAdd((unsigned int*)&accums[1], 0u);
            out[0] = L / ((float)C + 1e-8f);
        }
    }
}

extern "C" void kernel_launch(void* const* d_in, const int* in_sizes, int n_in,
                              void* d_out, int out_size, void* d_ws, size_t ws_size,
                              hipStream_t stream) {
    (void)in_sizes; (void)n_in; (void)out_size; (void)ws_size;
    const int* labels = (const int*)d_in[0];
    const float* emb  = (const float*)d_in[1];
    char* ws = (char*)d_ws;
    float* Dm   = (float*)ws;                     // 1 MB
    int*   ctrl = (int*)(ws + (1u << 20));        // 3 ints

    k_dist<<<136, 512, 0, stream>>>(emb, Dm, ctrl);
    k_mine<<<128, 256, 0, stream>>>(labels, Dm, (float*)ctrl, (float*)d_out, 128);
}